// Round 6
// baseline (87.831 us; speedup 1.0000x reference)
//
#include <hip/hip_runtime.h>
#include <hip/hip_cooperative_groups.h>

namespace cg = cooperative_groups;

#define LOG2F_ 0.69314718056f
#define N_TGT_WAVES 1920   // 96 (s,b) x 20 targets
#define N_OBJ_UNITS 576    // s0:96 units(169), s1:96 units(676), s2:384 chunks(676)
#define N_BLOCKS 276       // 240 target blocks + 36 obj blocks, 8 waves each
#define N_SLOTS 276

__device__ __forceinline__ float softplus_f(float x) {
    return fmaxf(x, 0.f) + log1pf(expf(-fabsf(x)));
}

__device__ __forceinline__ void scale_params(int s, const float*& p, int& G, float& inv_stride,
                                             const float* p0, const float* p1, const float* p2) {
    if (s == 0)      { p = p0; G = 13; inv_stride = 1.f / 32.f; }
    else if (s == 1) { p = p1; G = 26; inv_stride = 1.f / 16.f; }
    else             { p = p2; G = 52; inv_stride = 1.f / 8.f;  }
}

// Cooperative single kernel. 276 blocks x 512 threads (8 waves).
//  global wave w = blk*8+wave:
//   w in [0,1920):  one target (sb,t) — gather 85 channels, per-target loss.
//   w in [1920,2208): obj wave — two obj units, each softplus-sum * 50*nv/32.
//  Block sums its 8 wave partials -> slots[blk]; grid.sync(); block 0 reduces.
__global__ __launch_bounds__(512)
void yolo_coop(const float* __restrict__ p0,
               const float* __restrict__ p1,
               const float* __restrict__ p2,
               const float* __restrict__ targets,
               const float* __restrict__ anchors,
               float* __restrict__ slots,
               float* __restrict__ out) {
    int wave = threadIdx.x >> 6;
    int lane = threadIdx.x & 63;
    int w    = blockIdx.x * 8 + wave;
    float contrib = 0.f;   // lane 0 holds wave contribution after reduce

    if (w < N_TGT_WAVES) {
        // ---------------- target wave ----------------
        int sb = w / 20;
        int t  = w - sb * 20;
        int s  = sb >> 5, b = sb & 31;

        const float* p; int G; float inv_stride;
        scale_params(s, p, G, inv_stride, p0, p1, p2);
        int GG = G * G;

        const float* tg = targets + (b * 20 + t) * 5;
        float tc_f = tg[0];
        float x1 = tg[1], y1 = tg[2], x2 = tg[3], y2 = tg[4];
        float gx = x1 * inv_stride, gy = y1 * inv_stride;
        float gw_ = (x2 - x1) * inv_stride, gh_ = (y2 - y1) * inv_stride;
        float fgi = floorf(gx), fgj = floorf(gy);
        bool valid = (fgi >= 0.f) && (fgi < (float)G) && (fgj >= 0.f) && (fgj < (float)G);
        float vm = valid ? 1.f : 0.f;
        int gi = (int)fminf(fmaxf(fgi, 0.f), (float)(G - 1));
        int gj = (int)fminf(fmaxf(fgj, 0.f), (float)(G - 1));

        // best anchor, first-max (strict >) semantics
        float best_iou = -1.f, best_aw = 0.f, best_ah = 0.f; int best = 0;
        for (int a = 0; a < 3; ++a) {
            float aw = anchors[(s * 3 + a) * 2 + 0] * inv_stride;
            float ah = anchors[(s * 3 + a) * 2 + 1] * inv_stride;
            float inter = fminf(gw_, aw) * fminf(gh_, ah);
            float uni   = gw_ * gh_ + aw * ah - inter;
            float iou   = inter / (uni + 1e-16f);
            if (iou > best_iou) { best_iou = iou; best = a; best_aw = aw; best_ah = ah; }
        }

        float gtx = gx - (float)gi, gty = gy - (float)gj;
        float gtw = logf(fmaxf(gw_, 1e-16f) / (best_aw + 1e-16f));
        float gth = logf(fmaxf(gh_, 1e-16f) / (best_ah + 1e-16f));
        int   tc  = (int)tc_f;

        const float* base = p + ((size_t)(b * 255 + best * 85)) * GG + gj * G + gi;
        float v0 = base[(size_t)lane * GG];
        float v1 = (lane < 21) ? base[(size_t)(64 + lane) * GG] : 0.f;

        float term;
        int c = lane;
        if (c == 0) {
            float px = 1.f / (1.f + expf(-v0));
            term = 5.f * (px - gtx) * (px - gtx);
        } else if (c == 1) {
            float py = 1.f / (1.f + expf(-v0));
            term = 5.f * (py - gty) * (py - gty);
        } else if (c == 2) {
            term = 5.f * (v0 - gtw) * (v0 - gtw);
        } else if (c == 3) {
            term = 5.f * (v0 - gth) * (v0 - gth);
        } else if (c == 4) {
            term = softplus_f(-v0) - 50.f * softplus_f(v0);
        } else {
            term = softplus_f(v0) - ((c - 5 == tc) ? v0 : 0.f);
        }
        if (lane < 21) {
            int c1 = 64 + lane;
            term += softplus_f(v1) - ((c1 - 5 == tc) ? v1 : 0.f);
        }

        for (int off = 32; off > 0; off >>= 1) term += __shfl_down(term, off);
        if (lane == 0) contrib = vm * (term + 50.f * LOG2F_) * (1.f / 32.f);
    } else {
        // ---------------- obj wave: two units ----------------
        int u2 = w - N_TGT_WAVES;          // 0..287
        for (int k = 0; k < 2; ++k) {
            int u = u2 * 2 + k;            // 0..575
            int s, b, a, off, len;
            if (u < 96)       { s = 0; b = u / 3;  a = u - (u / 3) * 3;  off = 0; len = 169; }
            else if (u < 192) { int v = u - 96;  s = 1; b = v / 3; a = v - (v / 3) * 3; off = 0; len = 676; }
            else              { int v = u - 192; s = 2; b = v / 12; int r = v - (v / 12) * 12;
                                a = r >> 2; off = (r & 3) * 676; len = 676; }

            const float* p; int G; float inv_stride;
            scale_params(s, p, G, inv_stride, p0, p1, p2);
            int GG = G * G;

            const float* src = p + ((size_t)(b * 255 + a * 85 + 4)) * GG + off;
            float sum = 0.f;
            for (int i = lane; i < len; i += 64)
                sum += softplus_f(src[i]);
            for (int o = 32; o > 0; o >>= 1) sum += __shfl_down(sum, o);

            // nv for this (s,b): lanes 0..19 test target validity at this scale
            bool valid = false;
            if (lane < 20) {
                const float* tg = targets + (b * 20 + lane) * 5;
                float gx = tg[1] * inv_stride, gy = tg[2] * inv_stride;
                float fgi = floorf(gx), fgj = floorf(gy);
                valid = (fgi >= 0.f) && (fgi < (float)G) &&
                        (fgj >= 0.f) && (fgj < (float)G);
            }
            float nv = (float)__popcll(__ballot(valid));
            if (lane == 0) contrib += (50.f / 32.f) * nv * sum;
        }
    }

    __shared__ float partl[8];
    if (lane == 0) partl[wave] = contrib;
    __syncthreads();
    if (threadIdx.x == 0) {
        float s8 = 0.f;
        #pragma unroll
        for (int i = 0; i < 8; ++i) s8 += partl[i];
        slots[blockIdx.x] = s8;
    }
    __threadfence();

    cg::this_grid().sync();

    if (blockIdx.x == 0) {
        __shared__ float red[512];
        int tid = threadIdx.x;
        red[tid] = (tid < N_SLOTS) ? slots[tid] : 0.f;
        __syncthreads();
        for (int off = 256; off > 0; off >>= 1) {
            if (tid < off) red[tid] += red[tid + off];
            __syncthreads();
        }
        if (tid == 0) out[0] = red[0];
    }
}

extern "C" void kernel_launch(void* const* d_in, const int* in_sizes, int n_in,
                              void* d_out, int out_size, void* d_ws, size_t ws_size,
                              hipStream_t stream) {
    const float* p0      = (const float*)d_in[0];
    const float* p1      = (const float*)d_in[1];
    const float* p2      = (const float*)d_in[2];
    const float* targets = (const float*)d_in[3];
    const float* anchors = (const float*)d_in[4];
    float* slots = (float*)d_ws;
    float* out   = (float*)d_out;

    void* args[] = { (void*)&p0, (void*)&p1, (void*)&p2,
                     (void*)&targets, (void*)&anchors,
                     (void*)&slots, (void*)&out };
    hipLaunchCooperativeKernel(reinterpret_cast<void*>(yolo_coop),
                               dim3(N_BLOCKS), dim3(512), args, 0, stream);
}

// Round 7
// 16.288 us; speedup vs baseline: 5.3922x; 5.3922x over previous
//
#include <hip/hip_runtime.h>

#define LOG2F_ 0.69314718056f
#define N_TGT_WAVES 1920   // 96 (s,b) x 20 targets
#define N_BLOCKS 624       // 2496 waves: 1920 target + 576 obj-chunk
#define MAGIC 0x7F3A9C51u

__device__ __forceinline__ float softplus_f(float x) {
    return fmaxf(x, 0.f) + log1pf(expf(-fabsf(x)));
}

// Single dispatch. 624 blocks x 4 waves; every wave is an independent unit.
//  waves [0,1920): one target (sb,t) — gather 85 channels, per-target loss.
//  waves [1920,2496): one obj chunk (s,b,a,chunk) — softplus-sum * 50*nv_sb/32.
// Each block publishes its partial as (MAGIC<<32)|float_bits via device-scope
// release store; block 0 acquire-spins on all slots, then reduces in fixed
// order (bitwise deterministic) and writes d_out. No fills, no atomicsAdd,
// no grid barrier, no zero-init requirement.
__global__ __launch_bounds__(256)
void yolo_onepass(const float* __restrict__ p0,
                  const float* __restrict__ p1,
                  const float* __restrict__ p2,
                  const float* __restrict__ targets,
                  const float* __restrict__ anchors,
                  unsigned long long* __restrict__ slots,
                  float* __restrict__ out) {
    int wave = threadIdx.x >> 6;
    int lane = threadIdx.x & 63;
    int w    = blockIdx.x * 4 + wave;
    float contrib = 0.f;   // lane 0 holds wave contribution after reduce

    if (w < N_TGT_WAVES) {
        // ---------------- target wave ----------------
        int sb = w / 20;
        int t  = w - sb * 20;
        int s  = sb >> 5, b = sb & 31;

        const float* p; int G; float inv_stride;
        if (s == 0)      { p = p0; G = 13; inv_stride = 1.f / 32.f; }
        else if (s == 1) { p = p1; G = 26; inv_stride = 1.f / 16.f; }
        else             { p = p2; G = 52; inv_stride = 1.f / 8.f;  }
        int GG = G * G;

        const float* tg = targets + (b * 20 + t) * 5;
        float tc_f = tg[0];
        float x1 = tg[1], y1 = tg[2], x2 = tg[3], y2 = tg[4];
        float gx = x1 * inv_stride, gy = y1 * inv_stride;
        float gw_ = (x2 - x1) * inv_stride, gh_ = (y2 - y1) * inv_stride;
        float fgi = floorf(gx), fgj = floorf(gy);
        bool valid = (fgi >= 0.f) && (fgi < (float)G) && (fgj >= 0.f) && (fgj < (float)G);
        float vm = valid ? 1.f : 0.f;
        int gi = (int)fminf(fmaxf(fgi, 0.f), (float)(G - 1));
        int gj = (int)fminf(fmaxf(fgj, 0.f), (float)(G - 1));

        // best anchor, first-max (strict >) semantics
        float best_iou = -1.f, best_aw = 0.f, best_ah = 0.f; int best = 0;
        for (int a = 0; a < 3; ++a) {
            float aw = anchors[(s * 3 + a) * 2 + 0] * inv_stride;
            float ah = anchors[(s * 3 + a) * 2 + 1] * inv_stride;
            float inter = fminf(gw_, aw) * fminf(gh_, ah);
            float uni   = gw_ * gh_ + aw * ah - inter;
            float iou   = inter / (uni + 1e-16f);
            if (iou > best_iou) { best_iou = iou; best = a; best_aw = aw; best_ah = ah; }
        }

        float gtx = gx - (float)gi, gty = gy - (float)gj;
        float gtw = logf(fmaxf(gw_, 1e-16f) / (best_aw + 1e-16f));
        float gth = logf(fmaxf(gh_, 1e-16f) / (best_ah + 1e-16f));
        int   tc  = (int)tc_f;

        const float* base = p + ((size_t)(b * 255 + best * 85)) * GG + gj * G + gi;
        float v0 = base[(size_t)lane * GG];
        float v1 = (lane < 21) ? base[(size_t)(64 + lane) * GG] : 0.f;

        float term;
        int c = lane;
        if (c == 0) {
            float px = 1.f / (1.f + expf(-v0));
            term = 5.f * (px - gtx) * (px - gtx);
        } else if (c == 1) {
            float py = 1.f / (1.f + expf(-v0));
            term = 5.f * (py - gty) * (py - gty);
        } else if (c == 2) {
            term = 5.f * (v0 - gtw) * (v0 - gtw);
        } else if (c == 3) {
            term = 5.f * (v0 - gth) * (v0 - gth);
        } else if (c == 4) {
            term = softplus_f(-v0) - 50.f * softplus_f(v0);
        } else {
            term = softplus_f(v0) - ((c - 5 == tc) ? v0 : 0.f);
        }
        if (lane < 21) {
            int c1 = 64 + lane;
            term += softplus_f(v1) - ((c1 - 5 == tc) ? v1 : 0.f);
        }

        for (int off = 32; off > 0; off >>= 1) term += __shfl_down(term, off);
        if (lane == 0) contrib = vm * (term + 50.f * LOG2F_) * (1.f / 32.f);
    } else {
        // ---------------- obj chunk wave ----------------
        int u = w - N_TGT_WAVES;   // 0..575
        int s, b, a, off, len;
        if (u < 96)       { s = 0; b = u / 3;  a = u - (u / 3) * 3;  off = 0; len = 169; }
        else if (u < 192) { int v = u - 96;  s = 1; b = v / 3; a = v - (v / 3) * 3; off = 0; len = 676; }
        else              { int v = u - 192; s = 2; b = v / 12; int r = v - (v / 12) * 12;
                            a = r >> 2; off = (r & 3) * 676; len = 676; }

        const float* p; int G; float inv_stride;
        if (s == 0)      { p = p0; G = 13; inv_stride = 1.f / 32.f; }
        else if (s == 1) { p = p1; G = 26; inv_stride = 1.f / 16.f; }
        else             { p = p2; G = 52; inv_stride = 1.f / 8.f;  }
        int GG = G * G;

        const float* src = p + ((size_t)(b * 255 + a * 85 + 4)) * GG + off;
        float sum = 0.f;
        for (int i = lane; i < len; i += 64)
            sum += softplus_f(src[i]);
        for (int o = 32; o > 0; o >>= 1) sum += __shfl_down(sum, o);

        // nv_sb: lanes 0..19 test target validity at this scale
        bool valid = false;
        if (lane < 20) {
            const float* tg = targets + (b * 20 + lane) * 5;
            float gx = tg[1] * inv_stride, gy = tg[2] * inv_stride;
            float fgi = floorf(gx), fgj = floorf(gy);
            valid = (fgi >= 0.f) && (fgi < (float)G) &&
                    (fgj >= 0.f) && (fgj < (float)G);
        }
        float nv = (float)__popcll(__ballot(valid));
        if (lane == 0) contrib = (50.f / 32.f) * nv * sum;
    }

    __shared__ float partl[4];
    if (lane == 0) partl[wave] = contrib;
    __syncthreads();
    if (threadIdx.x == 0) {
        float total = partl[0] + partl[1] + partl[2] + partl[3];
        unsigned long long packed =
            ((unsigned long long)MAGIC << 32) | (unsigned long long)__float_as_uint(total);
        __hip_atomic_store(&slots[blockIdx.x], packed,
                           __ATOMIC_RELEASE, __HIP_MEMORY_SCOPE_AGENT);
    }

    if (blockIdx.x != 0) return;

    // ---- block 0: consume all 624 slots, fixed-order deterministic sum ----
    float acc = 0.f;
    for (int i = threadIdx.x; i < N_BLOCKS; i += 256) {
        unsigned long long v = __hip_atomic_load(&slots[i],
                               __ATOMIC_ACQUIRE, __HIP_MEMORY_SCOPE_AGENT);
        while ((unsigned int)(v >> 32) != MAGIC) {
            v = __hip_atomic_load(&slots[i],
                                  __ATOMIC_ACQUIRE, __HIP_MEMORY_SCOPE_AGENT);
        }
        acc += __uint_as_float((unsigned int)v);
    }
    __shared__ float red[256];
    red[threadIdx.x] = acc;
    __syncthreads();
    for (int off = 128; off > 0; off >>= 1) {
        if (threadIdx.x < off) red[threadIdx.x] += red[threadIdx.x + off];
        __syncthreads();
    }
    if (threadIdx.x == 0) out[0] = red[0];
}

extern "C" void kernel_launch(void* const* d_in, const int* in_sizes, int n_in,
                              void* d_out, int out_size, void* d_ws, size_t ws_size,
                              hipStream_t stream) {
    const float* p0      = (const float*)d_in[0];
    const float* p1      = (const float*)d_in[1];
    const float* p2      = (const float*)d_in[2];
    const float* targets = (const float*)d_in[3];
    const float* anchors = (const float*)d_in[4];
    unsigned long long* slots = (unsigned long long*)d_ws;
    float* out = (float*)d_out;

    yolo_onepass<<<N_BLOCKS, 256, 0, stream>>>(p0, p1, p2, targets, anchors, slots, out);
}